// Round 17
// baseline (254.334 us; speedup 1.0000x reference)
//
#include <hip/hip_runtime.h>

// ChebNet classifier: 3x ChebConv(K=6) + 2x sparse pool + linear head.
// R16 -> R17: gathers were 1.5 waves/SIMD (100K threads), 2-level dependent
// loads unhidden. PAIR-SPLIT sprop: 2 threads per (row,chunk), parity-split
// edges, __shfl_xor(1) combine (pair = adjacent lanes). Doubles TLP and
// halves the serial edge chain. Applied to layer-0 c4 hops and the sprop
// halves of the packed layer-1/2 launches (sB 391 -> 782).

#define TPB 256
#define NB   318      // buckets = ceil(162500/512)
#define BCAP 8192     // per-bucket capacity
#define EPB  4096     // edges per block, phase A
#define TXS  800000LL // floats per Tx slot

static inline int gs(long long n) { return (int)((n + TPB - 1) / TPB); }

struct Desc5 {
    const int* rows[5];
    const int* cols[5];
    const float* vals[5];
    int eoff[6];
    int doff[5];
};

// ---------- phase A: bin edges by bucket (+ packed pad4 blocks) ----------

__global__ void k_binA_pad(Desc5 d, int* __restrict__ gbcnt, int2* __restrict__ binrec,
                           int Etot, int binBlocks,
                           const float* __restrict__ pos, float4* __restrict__ pdst,
                           int npos) {
    __shared__ int2 srec[EPB];
    __shared__ unsigned short sbuck[EPB];
    __shared__ int scnt[NB], sbase[NB], slcur[NB];
    int tid = threadIdx.x;
    if ((int)blockIdx.x >= binBlocks) {
        int i = (blockIdx.x - binBlocks) * 256 + tid;
        if (i < npos)
            pdst[i] = make_float4(pos[3 * i], pos[3 * i + 1], pos[3 * i + 2], 0.f);
        return;
    }
    int e0 = blockIdx.x * EPB;
    int ne = min(EPB, Etot - e0);
    for (int b = tid; b < NB; b += 256) scnt[b] = 0;
    __syncthreads();
    for (int i = tid; i < ne; i += 256) {
        int e = e0 + i;
        int s = 0;
        while (e >= d.eoff[s + 1]) ++s;
        int le = e - d.eoff[s];
        int grow = d.doff[s] + d.rows[s][le];
        int col = d.cols[s][le];
        int vb = (s >= 3) ? __float_as_int(d.vals[s][le]) : 0;
        int b = grow >> 9;
        srec[i] = make_int2(((grow & 511) << 17) | col, vb);
        sbuck[i] = (unsigned short)b;
        atomicAdd(&scnt[b], 1);
    }
    __syncthreads();
    for (int b = tid; b < NB; b += 256) {
        sbase[b] = scnt[b] > 0 ? atomicAdd(&gbcnt[b], scnt[b]) : 0;
        slcur[b] = 0;
    }
    __syncthreads();
    for (int i = tid; i < ne; i += 256) {
        int b = sbuck[i];
        int off = atomicAdd(&slcur[b], 1);
        binrec[(long long)b * BCAP + sbase[b] + off] = srec[i];
    }
}

// B1: bucket-base scan + row count/scan -> rowptr + dinv
__global__ void k_B1(const int* __restrict__ gbcnt, const int2* __restrict__ binrec,
                     int* __restrict__ rowptr, float* __restrict__ dinv,
                     int ntot, int ndinv, int Etot) {
    __shared__ int cnt[512], lexcl[512], wsum[4];
    int bucket = blockIdx.x, tid = threadIdx.x;
    int lane = tid & 63, wid = tid >> 6;
    {
        int v0 = (2 * tid < NB) ? gbcnt[2 * tid] : 0;
        int v1 = (2 * tid + 1 < NB) ? gbcnt[2 * tid + 1] : 0;
        int p = v0 + v1;
        int s = p;
#pragma unroll
        for (int off = 1; off < 64; off <<= 1) {
            int t = __shfl_up(s, off, 64);
            if (lane >= off) s += t;
        }
        if (lane == 63) wsum[wid] = s;
        __syncthreads();
        int add = 0;
        for (int w = 0; w < wid; ++w) add += wsum[w];
        int ep = add + s - p;
        lexcl[2 * tid] = ep; lexcl[2 * tid + 1] = ep + v0;
        __syncthreads();
    }
    int base = lexcl[bucket];
    __syncthreads();
    int ne = gbcnt[bucket];
    const int2* br = binrec + (long long)bucket * BCAP;
    cnt[2 * tid] = 0; cnt[2 * tid + 1] = 0;
    __syncthreads();
    for (int i = tid; i < ne; i += 256)
        atomicAdd(&cnt[br[i].x >> 17], 1);
    __syncthreads();
    int c0 = cnt[2 * tid], c1 = cnt[2 * tid + 1], p = c0 + c1;
    int s = p;
#pragma unroll
    for (int off = 1; off < 64; off <<= 1) {
        int t = __shfl_up(s, off, 64);
        if (lane >= off) s += t;
    }
    if (lane == 63) wsum[wid] = s;
    __syncthreads();
    int add = 0;
    for (int w = 0; w < wid; ++w) add += wsum[w];
    int ep = add + s - p;
    lexcl[2 * tid] = ep; lexcl[2 * tid + 1] = ep + c0;
    __syncthreads();
    int row0 = bucket << 9;
    int nrows = min(512, ntot - row0);
    for (int lr = tid; lr < nrows; lr += 256) {
        int grow = row0 + lr;
        rowptr[grow] = base + lexcl[lr];
        if (grow < ndinv) {
            int c = cnt[lr];
            dinv[grow] = c > 0 ? 1.0f / sqrtf((float)c) : 0.f;
        }
    }
    if (bucket == 0 && tid == 0) rowptr[ntot] = Etot;
}

// B2: place edges using rowptr (LDS-staged)
__global__ void k_B2(const int* __restrict__ gbcnt, const int2* __restrict__ binrec,
                     const int* __restrict__ rowptr, const float* __restrict__ dinv,
                     int2* __restrict__ rec, int ntot) {
    __shared__ int lbase[512], lcur[512];
    int bucket = blockIdx.x, tid = threadIdx.x;
    int row0 = bucket << 9;
    for (int i = tid; i < 512; i += 256) {
        int grow = row0 + i;
        lbase[i] = (grow < ntot) ? rowptr[grow] : 0;
        lcur[i] = 0;
    }
    __syncthreads();
    int ne = gbcnt[bucket];
    const int2* br = binrec + (long long)bucket * BCAP;
    for (int i = tid; i < ne; i += 256) {
        int2 r = br[i];
        int lr = r.x >> 17, col = r.x & 0x1FFFF;
        int grow = row0 + lr;
        int pos = lbase[lr] + atomicAdd(&lcur[lr], 1);
        float wv;
        if (grow < 100000)      wv = dinv[col];
        else if (grow < 125000) wv = dinv[100000 + col];
        else if (grow < 131250) wv = dinv[125000 + col];
        else                    wv = __int_as_float(r.y);
        rec[pos] = make_int2(col, __float_as_int(wv));
    }
}

// ---------- pair-split sprop bodies: 2 threads/row-chunk, shfl_xor combine ----------

// C == 4 (layer 0): pair-split, 2 chains per thread
__global__ void k_sprop_c4p(const int* __restrict__ rowptr, const int2* __restrict__ rec,
                            const float* __restrict__ dinv, const float* __restrict__ src,
                            const float* __restrict__ prev, float* __restrict__ dst,
                            int n, int mode) {
    int idx = blockIdx.x * blockDim.x + threadIdx.x;
    if (idx >= 2 * n) return;
    int r = idx >> 1, half = idx & 1;
    int s0 = rowptr[r], s1 = rowptr[r + 1];
    float4 a0 = make_float4(0.f, 0.f, 0.f, 0.f), a1 = a0;
    // this thread's edges: s0+half, step 2; two chains at step 4
    int j = s0 + half;
    for (; j + 2 < s1; j += 4) {
        int2 r0 = rec[j], r1 = rec[j + 2];
        float w0 = __int_as_float(r0.y), w1 = __int_as_float(r1.y);
        float4 s0v = *(const float4*)(src + (long long)r0.x * 4);
        float4 s1v = *(const float4*)(src + (long long)r1.x * 4);
        a0.x += w0 * s0v.x; a0.y += w0 * s0v.y; a0.z += w0 * s0v.z; a0.w += w0 * s0v.w;
        a1.x += w1 * s1v.x; a1.y += w1 * s1v.y; a1.z += w1 * s1v.z; a1.w += w1 * s1v.w;
    }
    if (j < s1) {
        int2 rr = rec[j];
        float w = __int_as_float(rr.y);
        float4 s = *(const float4*)(src + (long long)rr.x * 4);
        a0.x += w * s.x; a0.y += w * s.y; a0.z += w * s.z; a0.w += w * s.w;
    }
    a0.x += a1.x; a0.y += a1.y; a0.z += a1.z; a0.w += a1.w;
    // combine with partner lane (idx^1 lives in the same wave)
    a0.x += __shfl_xor(a0.x, 1, 64);
    a0.y += __shfl_xor(a0.y, 1, 64);
    a0.z += __shfl_xor(a0.z, 1, 64);
    a0.w += __shfl_xor(a0.w, 1, 64);
    if (half == 0) {
        float m = -dinv[r];
        long long o = (long long)r * 4;
        float4 out;
        if (mode) {
            float4 p = *(const float4*)(prev + o);
            out.x = 2.f * m * a0.x - p.x; out.y = 2.f * m * a0.y - p.y;
            out.z = 2.f * m * a0.z - p.z; out.w = 2.f * m * a0.w - p.w;
        } else {
            out.x = m * a0.x; out.y = m * a0.y; out.z = m * a0.z; out.w = m * a0.w;
        }
        *(float4*)(dst + o) = out;
    }
}

// pair-split 8-channel body (C=32): idx over n*4*2
__device__ __forceinline__
void sprop32p_body(const int* __restrict__ rowptr, const int2* __restrict__ rec,
                   const float* __restrict__ dinv, const float* __restrict__ src,
                   const float* __restrict__ prev, float* __restrict__ dst,
                   int n, int mode, int idx) {
    constexpr int C = 32;
    if (idx >= n * 8) return;
    int cid = idx >> 1, half = idx & 1;
    int r = cid >> 2, c4 = (cid & 3) * 8;
    int s0 = rowptr[r], s1 = rowptr[r + 1];
    float4 a0 = make_float4(0.f, 0.f, 0.f, 0.f), a1 = a0;
    for (int j = s0 + half; j < s1; j += 2) {
        int2 rr = rec[j];
        float w = __int_as_float(rr.y);
        const float* sp = src + (long long)rr.x * C + c4;
        float4 s0v = *(const float4*)(sp);
        float4 s1v = *(const float4*)(sp + 4);
        a0.x += w * s0v.x; a0.y += w * s0v.y; a0.z += w * s0v.z; a0.w += w * s0v.w;
        a1.x += w * s1v.x; a1.y += w * s1v.y; a1.z += w * s1v.z; a1.w += w * s1v.w;
    }
    a0.x += __shfl_xor(a0.x, 1, 64); a0.y += __shfl_xor(a0.y, 1, 64);
    a0.z += __shfl_xor(a0.z, 1, 64); a0.w += __shfl_xor(a0.w, 1, 64);
    a1.x += __shfl_xor(a1.x, 1, 64); a1.y += __shfl_xor(a1.y, 1, 64);
    a1.z += __shfl_xor(a1.z, 1, 64); a1.w += __shfl_xor(a1.w, 1, 64);
    if (half == 0) {
        float m = -dinv[r];
        long long o = (long long)r * C + c4;
        float4 o0, o1;
        if (mode) {
            float4 p0 = *(const float4*)(prev + o);
            float4 p1 = *(const float4*)(prev + o + 4);
            o0.x = 2.f * m * a0.x - p0.x; o0.y = 2.f * m * a0.y - p0.y;
            o0.z = 2.f * m * a0.z - p0.z; o0.w = 2.f * m * a0.w - p0.w;
            o1.x = 2.f * m * a1.x - p1.x; o1.y = 2.f * m * a1.y - p1.y;
            o1.z = 2.f * m * a1.z - p1.z; o1.w = 2.f * m * a1.w - p1.w;
        } else {
            o0.x = m * a0.x; o0.y = m * a0.y; o0.z = m * a0.z; o0.w = m * a0.w;
            o1.x = m * a1.x; o1.y = m * a1.y; o1.z = m * a1.z; o1.w = m * a1.w;
        }
        *(float4*)(dst + o) = o0;
        *(float4*)(dst + o + 4) = o1;
    }
}

// pair-split 4-channel body (C=64): idx over n*16*2
__device__ __forceinline__
void sprop64p_body(const int* __restrict__ rowptr, const int2* __restrict__ rec,
                   const float* __restrict__ dinv, const float* __restrict__ src,
                   const float* __restrict__ prev, float* __restrict__ dst,
                   int n, int mode, int idx) {
    constexpr int C = 64, C4 = 16;
    if (idx >= n * C4 * 2) return;
    int cid = idx >> 1, half = idx & 1;
    int r = cid / C4, c4 = (cid - r * C4) * 4;
    int s0 = rowptr[r], s1 = rowptr[r + 1];
    float4 a0 = make_float4(0.f, 0.f, 0.f, 0.f), a1 = a0;
    int j = s0 + half;
    for (; j + 2 < s1; j += 4) {
        int2 r0 = rec[j], r1 = rec[j + 2];
        float w0 = __int_as_float(r0.y), w1 = __int_as_float(r1.y);
        float4 s0v = *(const float4*)(src + (long long)r0.x * C + c4);
        float4 s1v = *(const float4*)(src + (long long)r1.x * C + c4);
        a0.x += w0 * s0v.x; a0.y += w0 * s0v.y; a0.z += w0 * s0v.z; a0.w += w0 * s0v.w;
        a1.x += w1 * s1v.x; a1.y += w1 * s1v.y; a1.z += w1 * s1v.z; a1.w += w1 * s1v.w;
    }
    if (j < s1) {
        int2 rr = rec[j];
        float w = __int_as_float(rr.y);
        float4 s = *(const float4*)(src + (long long)rr.x * C + c4);
        a0.x += w * s.x; a0.y += w * s.y; a0.z += w * s.z; a0.w += w * s.w;
    }
    a0.x += a1.x; a0.y += a1.y; a0.z += a1.z; a0.w += a1.w;
    a0.x += __shfl_xor(a0.x, 1, 64); a0.y += __shfl_xor(a0.y, 1, 64);
    a0.z += __shfl_xor(a0.z, 1, 64); a0.w += __shfl_xor(a0.w, 1, 64);
    if (half == 0) {
        float m = -dinv[r];
        long long o = (long long)r * C + c4;
        float4 out;
        if (mode) {
            float4 p = *(const float4*)(prev + o);
            out.x = 2.f * m * a0.x - p.x; out.y = 2.f * m * a0.y - p.y;
            out.z = 2.f * m * a0.z - p.z; out.w = 2.f * m * a0.w - p.w;
        } else {
            out.x = m * a0.x; out.y = m * a0.y; out.z = m * a0.z; out.w = m * a0.w;
        }
        *(float4*)(dst + o) = out;
    }
}

// ---------- per-k gemm body: part_k = tx_k @ W[k] (forced-loop, no spill) ----------

template <int CIN, int COUT, int NT>
__device__ __forceinline__
void gemm1k_body(float* __restrict__ part, const float* __restrict__ txbase,
                 const float* __restrict__ W, int n, int pstride, int kg, int idx) {
    constexpr int CO4 = COUT / 4;
    int per = (n / NT) * CO4;
    if (idx >= per) return;
    int tile = idx / CO4, co = (idx - tile * CO4) * 4;
    int node0 = tile * NT;
    float4 acc[NT];
#pragma unroll
    for (int i = 0; i < NT; ++i) acc[i] = make_float4(0.f, 0.f, 0.f, 0.f);
    const float* xb = txbase + (long long)kg * TXS + (long long)node0 * CIN;
    const float* Wk = W + (long long)kg * CIN * COUT + co;
#pragma unroll 1
    for (int c4 = 0; c4 < CIN / 4; ++c4) {
        const float* Wr = Wk + c4 * 4 * COUT;
        float4 w0 = *(const float4*)(Wr);
        float4 w1 = *(const float4*)(Wr + COUT);
        float4 w2 = *(const float4*)(Wr + 2 * COUT);
        float4 w3 = *(const float4*)(Wr + 3 * COUT);
#pragma unroll
        for (int i = 0; i < NT; ++i) {
            float4 xv = *(const float4*)(xb + i * CIN + c4 * 4);
            acc[i].x += xv.x * w0.x + xv.y * w1.x + xv.z * w2.x + xv.w * w3.x;
            acc[i].y += xv.x * w0.y + xv.y * w1.y + xv.z * w2.y + xv.w * w3.y;
            acc[i].z += xv.x * w0.z + xv.y * w1.z + xv.z * w2.z + xv.w * w3.z;
            acc[i].w += xv.x * w0.w + xv.y * w1.w + xv.z * w2.w + xv.w * w3.w;
        }
    }
    float* op = part + (long long)kg * pstride + (long long)node0 * COUT + co;
#pragma unroll
    for (int i = 0; i < NT; ++i)
        *(float4*)(op + (long long)i * COUT) = acc[i];
}

// ---------- packed launches: sprop hop (blocks [0,SB)) + gemm_k (rest) ----------

__global__ __launch_bounds__(256, 4)
void k_pack1(const int* __restrict__ rowptr, const int2* __restrict__ rec,
             const float* __restrict__ dinv, const float* __restrict__ src,
             const float* __restrict__ prev, float* __restrict__ dst,
             int n, int mode, float* __restrict__ part,
             const float* __restrict__ txbase, const float* __restrict__ W,
             int pstride, int kg, int spropBlocks) {
    int bid = blockIdx.x;
    if (bid < spropBlocks)
        sprop32p_body(rowptr, rec, dinv, src, prev, dst, n, mode,
                      bid * 256 + threadIdx.x);
    else
        gemm1k_body<32, 64, 4>(part, txbase, W, n, pstride, kg,
                               (bid - spropBlocks) * 256 + threadIdx.x);
}

__global__ __launch_bounds__(256, 4)
void k_pack2(const int* __restrict__ rowptr, const int2* __restrict__ rec,
             const float* __restrict__ dinv, const float* __restrict__ src,
             const float* __restrict__ prev, float* __restrict__ dst,
             int n, int mode, float* __restrict__ part,
             const float* __restrict__ txbase, const float* __restrict__ W,
             int pstride, int kg, int spropBlocks) {
    int bid = blockIdx.x;
    if (bid < spropBlocks)
        sprop64p_body(rowptr, rec, dinv, src, prev, dst, n, mode,
                      bid * 256 + threadIdx.x);
    else
        gemm1k_body<64, 128, 2>(part, txbase, W, n, pstride, kg,
                                (bid - spropBlocks) * 256 + threadIdx.x);
}

// standalone trailing gemm (k = 5)
template <int CIN, int COUT, int NT>
__global__ __launch_bounds__(256, 4)
void k_gemm1k(float* __restrict__ part, const float* __restrict__ txbase,
              const float* __restrict__ W, int n, int pstride, int kg) {
    gemm1k_body<CIN, COUT, NT>(part, txbase, W, n, pstride, kg,
                               blockIdx.x * 256 + threadIdx.x);
}

// layer-0 FINAL hop fused with the out-GEMM (node-local)
__global__ __launch_bounds__(256, 4)
void k_conv0_final(const int* __restrict__ rowptr, const int2* __restrict__ rec,
                   const float* __restrict__ dinv, const float* __restrict__ txbase,
                   const float* __restrict__ W, const float* __restrict__ b,
                   float* __restrict__ out, int n) {
    int r = blockIdx.x * blockDim.x + threadIdx.x;
    if (r >= n) return;
    const float* src = txbase + 4 * TXS;   // tx4
    int s0 = rowptr[r], s1 = rowptr[r + 1];
    float4 a0 = make_float4(0.f, 0.f, 0.f, 0.f);
    float4 a1 = a0;
    int j = s0;
    if ((j & 1) && j < s1) {
        int2 rr = rec[j];
        float w = __int_as_float(rr.y);
        float4 s = *(const float4*)(src + (long long)rr.x * 4);
        a0.x += w * s.x; a0.y += w * s.y; a0.z += w * s.z;
        ++j;
    }
    for (; j + 2 <= s1; j += 2) {
        int4 q = *(const int4*)(rec + j);
        float wa = __int_as_float(q.y), wb = __int_as_float(q.w);
        float4 sa = *(const float4*)(src + (long long)q.x * 4);
        float4 sb = *(const float4*)(src + (long long)q.z * 4);
        a0.x += wa * sa.x; a0.y += wa * sa.y; a0.z += wa * sa.z;
        a1.x += wb * sb.x; a1.y += wb * sb.y; a1.z += wb * sb.z;
    }
    if (j < s1) {
        int2 rr = rec[j];
        float w = __int_as_float(rr.y);
        float4 s = *(const float4*)(src + (long long)rr.x * 4);
        a0.x += w * s.x; a0.y += w * s.y; a0.z += w * s.z;
    }
    a0.x += a1.x; a0.y += a1.y; a0.z += a1.z;
    float m = -dinv[r];
    float4 xv[6];
#pragma unroll
    for (int k = 0; k < 5; ++k)
        xv[k] = *(const float4*)(txbase + (long long)k * TXS + (long long)r * 4);
    xv[5].x = 2.f * m * a0.x - xv[3].x;
    xv[5].y = 2.f * m * a0.y - xv[3].y;
    xv[5].z = 2.f * m * a0.z - xv[3].z;
    float* op = out + (long long)r * 32;
#pragma unroll 1
    for (int co4 = 0; co4 < 8; ++co4) {
        float4 acc = *(const float4*)(b + co4 * 4);
#pragma unroll
        for (int k = 0; k < 6; ++k) {
            const float* Wk = W + k * 96 + co4 * 4;
            float4 w0 = *(const float4*)(Wk);
            float4 w1 = *(const float4*)(Wk + 32);
            float4 w2 = *(const float4*)(Wk + 64);
            acc.x += xv[k].x * w0.x + xv[k].y * w1.x + xv[k].z * w2.x;
            acc.y += xv[k].x * w0.y + xv[k].y * w1.y + xv[k].z * w2.y;
            acc.z += xv[k].x * w0.z + xv[k].y * w1.z + xv[k].z * w2.z;
            acc.w += xv[k].x * w0.w + xv[k].y * w1.w + xv[k].z * w2.w;
        }
        *(float4*)(op + co4 * 4) = acc;
    }
}

// ---------- pool0: out[r] = sum_j val_j * relu(x[col_j]) ----------

template <int C>
__global__ void k_spool4_t(const int* __restrict__ rowptr, const int2* __restrict__ rec,
                           const float* __restrict__ x, float* __restrict__ out, int n) {
    constexpr int C4 = C / 4;
    int idx = blockIdx.x * blockDim.x + threadIdx.x;
    if (idx >= n * C4) return;
    int r = idx / C4, c4 = (idx - r * C4) * 4;
    int s0 = rowptr[r], s1 = rowptr[r + 1];
    float4 acca = make_float4(0.f, 0.f, 0.f, 0.f);
    float4 accb = make_float4(0.f, 0.f, 0.f, 0.f);
    int j = s0;
    if ((j & 1) && j < s1) {
        int2 rr = rec[j];
        float v = __int_as_float(rr.y);
        float4 s = *(const float4*)(x + (long long)rr.x * C + c4);
        acca.x += v * fmaxf(s.x, 0.f); acca.y += v * fmaxf(s.y, 0.f);
        acca.z += v * fmaxf(s.z, 0.f); acca.w += v * fmaxf(s.w, 0.f);
        ++j;
    }
    for (; j + 2 <= s1; j += 2) {
        int4 q = *(const int4*)(rec + j);
        float va = __int_as_float(q.y), vb = __int_as_float(q.w);
        float4 sa = *(const float4*)(x + (long long)q.x * C + c4);
        float4 sb = *(const float4*)(x + (long long)q.z * C + c4);
        acca.x += va * fmaxf(sa.x, 0.f); acca.y += va * fmaxf(sa.y, 0.f);
        acca.z += va * fmaxf(sa.z, 0.f); acca.w += va * fmaxf(sa.w, 0.f);
        accb.x += vb * fmaxf(sb.x, 0.f); accb.y += vb * fmaxf(sb.y, 0.f);
        accb.z += vb * fmaxf(sb.z, 0.f); accb.w += vb * fmaxf(sb.w, 0.f);
    }
    if (j < s1) {
        int2 rr = rec[j];
        float v = __int_as_float(rr.y);
        float4 s = *(const float4*)(x + (long long)rr.x * C + c4);
        acca.x += v * fmaxf(s.x, 0.f); acca.y += v * fmaxf(s.y, 0.f);
        acca.z += v * fmaxf(s.z, 0.f); acca.w += v * fmaxf(s.w, 0.f);
    }
    acca.x += accb.x; acca.y += accb.y; acca.z += accb.z; acca.w += accb.w;
    *(float4*)(out + (long long)r * C + c4) = acca;
}

// ---------- pool1 fused with layer-1 partial reduce + bias + relu ----------

template <int C, int KSPLIT>
__global__ void k_pool_f(const int* __restrict__ rowptr, const int2* __restrict__ rec,
                         const float* __restrict__ part, const float* __restrict__ bias,
                         float* __restrict__ out, int n, int partStride) {
    constexpr int C4 = C / 4;
    int idx = blockIdx.x * blockDim.x + threadIdx.x;
    if (idx >= n * C4) return;
    int r = idx / C4, c4 = (idx - r * C4) * 4;
    int s0 = rowptr[r], s1 = rowptr[r + 1];
    float4 bb = *(const float4*)(bias + c4);
    float4 acc = make_float4(0.f, 0.f, 0.f, 0.f);
    for (int j = s0; j < s1; ++j) {
        int2 rr = rec[j];
        float v = __int_as_float(rr.y);
        float4 x = bb;
#pragma unroll
        for (int s = 0; s < KSPLIT; ++s) {
            float4 p = *(const float4*)(part + (long long)s * partStride + (long long)rr.x * C + c4);
            x.x += p.x; x.y += p.y; x.z += p.z; x.w += p.w;
        }
        acc.x += v * fmaxf(x.x, 0.f); acc.y += v * fmaxf(x.y, 0.f);
        acc.z += v * fmaxf(x.z, 0.f); acc.w += v * fmaxf(x.w, 0.f);
    }
    *(float4*)(out + (long long)r * C + c4) = acc;
}

// ---------- linear head, fused with layer-2 partial reduce + bias ----------

__global__ void k_linear_partial_f(const float* __restrict__ lw,
                                   const float4* __restrict__ part,
                                   const float* __restrict__ b2,
                                   float* __restrict__ partials,
                                   int len4, int len, int nblk) {
    float acc[10];
#pragma unroll
    for (int j = 0; j < 10; ++j) acc[j] = 0.f;
    const float4* b2v = (const float4*)b2;
    for (int i = blockIdx.x * blockDim.x + threadIdx.x; i < len4;
         i += gridDim.x * blockDim.x) {
        float4 xv = b2v[i & 31];
#pragma unroll
        for (int s = 0; s < 6; ++s) {
            float4 p = part[s * 200000 + i];
            xv.x += p.x; xv.y += p.y; xv.z += p.z; xv.w += p.w;
        }
#pragma unroll
        for (int j = 0; j < 10; ++j) {
            float4 wv = *(const float4*)(lw + (long long)j * len + i * 4);
            acc[j] += xv.x * wv.x + xv.y * wv.y + xv.z * wv.z + xv.w * wv.w;
        }
    }
    __shared__ float lds[4][10];
    int wid = threadIdx.x >> 6, lane = threadIdx.x & 63;
#pragma unroll
    for (int j = 0; j < 10; ++j) {
        float v = acc[j];
        for (int off = 32; off > 0; off >>= 1) v += __shfl_down(v, off, 64);
        if (lane == 0) lds[wid][j] = v;
    }
    __syncthreads();
    if (threadIdx.x < 10) {
        float s = lds[0][threadIdx.x] + lds[1][threadIdx.x] +
                  lds[2][threadIdx.x] + lds[3][threadIdx.x];
        partials[threadIdx.x * nblk + blockIdx.x] = s;
    }
}

__global__ void k_linear_final(const float* __restrict__ partials,
                               const float* __restrict__ lb,
                               float* __restrict__ out, int nblk) {
    int j = threadIdx.x >> 6, lane = threadIdx.x & 63;
    float v = 0.f;
    for (int b = lane; b < nblk; b += 64) v += partials[j * nblk + b];
    for (int off = 32; off > 0; off >>= 1) v += __shfl_down(v, off, 64);
    if (lane == 0) out[j] = lb[j] + v;
}

extern "C" void kernel_launch(void* const* d_in, const int* in_sizes, int n_in,
                              void* d_out, int out_size, void* d_ws, size_t ws_size,
                              hipStream_t stream) {
    const int cN0 = 100000, cN1 = 25000, cN2 = 6250;
    const int cE0 = 600000, cE1 = 150000, cE2 = 40000;
    const int NBLK = 512;

    const float* pos = (const float*)d_in[0];
    const int*   ei0 = (const int*)d_in[1];
    const int*   ei1 = (const int*)d_in[2];
    const int*   ei2 = (const int*)d_in[3];
    const int*   d0r = (const int*)d_in[4];
    const int*   d0c = (const int*)d_in[5];
    const float* d0v = (const float*)d_in[6];
    const int*   d1r = (const int*)d_in[7];
    const int*   d1c = (const int*)d_in[8];
    const float* d1v = (const float*)d_in[9];
    const float* W0  = (const float*)d_in[10];
    const float* b0  = (const float*)d_in[11];
    const float* W1  = (const float*)d_in[12];
    const float* b1  = (const float*)d_in[13];
    const float* W2  = (const float*)d_in[14];
    const float* b2  = (const float*)d_in[15];
    const float* lw  = (const float*)d_in[16];
    const float* lb  = (const float*)d_in[17];
    float* outZ = (float*)d_out;

    // concatenated row space: g0 g1 g2 p0 p1
    const int ntot = cN0 + cN1 + cN2 + cN1 + cN2;          // 162500
    const int Etot = cE0 + cE1 + cE2 + cN0 + cN1;          // 915000
    const int Eg   = cE0 + cE1 + cE2;                      // 790000
    const int ndinv = cN0 + cN1 + cN2;                     // 131250
    const int doff0 = 0, doff1 = cN0, doff2 = cN0 + cN1,
              doffp0 = doff2 + cN2, doffp1 = doffp0 + cN1;

    // workspace layout (4B units); int2/float4 bases 16B-aligned
    int*   iws    = (int*)d_ws;
    int*   gbcnt  = iws;                          // 320
    int*   rowptr = gbcnt + 320;                  // 162504
    float* dinv   = (float*)(rowptr + 162504);    // 131256
    int2*  binrec = (int2*)(dinv + 131256);       // NB*BCAP int2
    int2*  rec    = binrec + (long long)NB * BCAP;// 915000 int2
    float* txbuf  = (float*)(rec + 915000);       // 6 x TXS (slot 0 = x)
    float* part   = txbuf + 6 * TXS;              // 6 x 1600000 (layer-1 max)
    float* bufOut = part + 9600000;               // 3200000
    float* lpart  = bufOut + 3200000;             // 5120

    Desc5 d;
    d.rows[0] = ei0;        d.cols[0] = ei0 + cE0; d.vals[0] = nullptr;
    d.rows[1] = ei1;        d.cols[1] = ei1 + cE1; d.vals[1] = nullptr;
    d.rows[2] = ei2;        d.cols[2] = ei2 + cE2; d.vals[2] = nullptr;
    d.rows[3] = d0r;        d.cols[3] = d0c;       d.vals[3] = d0v;
    d.rows[4] = d1r;        d.cols[4] = d1c;       d.vals[4] = d1v;
    d.eoff[0] = 0;
    d.eoff[1] = cE0;
    d.eoff[2] = cE0 + cE1;
    d.eoff[3] = Eg;
    d.eoff[4] = Eg + cN0;
    d.eoff[5] = Etot;
    d.doff[0] = doff0; d.doff[1] = doff1; d.doff[2] = doff2;
    d.doff[3] = doffp0; d.doff[4] = doffp1;

    // ---- binned CSR build + packed pad4 ----
    hipMemsetAsync(gbcnt, 0, (size_t)NB * 4, stream);
    int binBlocks = (Etot + EPB - 1) / EPB;               // 224
    int padBlocks = gs(cN0);                              // 391
    k_binA_pad<<<binBlocks + padBlocks, TPB, 0, stream>>>(
        d, gbcnt, binrec, Etot, binBlocks, pos, (float4*)txbuf, cN0);
    k_B1<<<NB, TPB, 0, stream>>>(gbcnt, binrec, rowptr, dinv, ntot, ndinv, Etot);
    k_B2<<<NB, TPB, 0, stream>>>(gbcnt, binrec, rowptr, dinv, rec, ntot);

    // ---- layer 0: pair-split hops 1..4, fused hop-5 + out-GEMM; pool0 ----
    for (int k = 1; k <= 4; ++k) {
        const float* src = txbuf + (long long)(k - 1) * TXS;
        const float* prev = (k >= 2) ? txbuf + (long long)(k - 2) * TXS : nullptr;
        float* dst = txbuf + (long long)k * TXS;
        k_sprop_c4p<<<gs((long long)cN0 * 2), TPB, 0, stream>>>(
            rowptr + doff0, rec, dinv + doff0, src, prev, dst, cN0, k >= 2 ? 1 : 0);
    }
    k_conv0_final<<<gs(cN0), TPB, 0, stream>>>(
        rowptr + doff0, rec, dinv + doff0, txbuf, W0, b0, bufOut, cN0);
    k_spool4_t<32><<<gs((long long)cN1 * 8), TPB, 0, stream>>>(
        rowptr + doffp0, rec, bufOut, txbuf, cN1);

    // ---- layer 1: packed hops (pair-split sprop + gemm_{k-1}); g5; pool ----
    {
        const int pstride = cN1 * 64;                      // 1600000
        int sB = gs((long long)cN1 * 8);                   // 782 (pair-split)
        int gB = gs((long long)(cN1 / 4) * 16);            // 391
        for (int k = 1; k <= 5; ++k) {
            const float* src = txbuf + (long long)(k - 1) * TXS;
            const float* prev = (k >= 2) ? txbuf + (long long)(k - 2) * TXS : nullptr;
            float* dst = txbuf + (long long)k * TXS;
            k_pack1<<<sB + gB, TPB, 0, stream>>>(
                rowptr + doff1, rec, dinv + doff1, src, prev, dst, cN1,
                k >= 2 ? 1 : 0, part, txbuf, W1, pstride, k - 1, sB);
        }
        k_gemm1k<32, 64, 4><<<gB, TPB, 0, stream>>>(part, txbuf, W1, cN1, pstride, 5);
        k_pool_f<64, 6><<<gs((long long)cN2 * 16), TPB, 0, stream>>>(
            rowptr + doffp1, rec, part, b1, txbuf, cN2, pstride);
    }

    // ---- layer 2: packed hops (pair-split); g5; fused linear head ----
    {
        const int pstride = cN2 * 128;                     // 800000
        int sB = gs((long long)cN2 * 32);                  // 782 (pair-split)
        int gB = gs((long long)(cN2 / 2) * 32);            // 391
        for (int k = 1; k <= 5; ++k) {
            const float* src = txbuf + (long long)(k - 1) * TXS;
            const float* prev = (k >= 2) ? txbuf + (long long)(k - 2) * TXS : nullptr;
            float* dst = txbuf + (long long)k * TXS;
            k_pack2<<<sB + gB, TPB, 0, stream>>>(
                rowptr + doff2, rec, dinv + doff2, src, prev, dst, cN2,
                k >= 2 ? 1 : 0, part, txbuf, W2, pstride, k - 1, sB);
        }
        k_gemm1k<64, 128, 2><<<gB, TPB, 0, stream>>>(part, txbuf, W2, cN2, pstride, 5);
        k_linear_partial_f<<<NBLK, TPB, 0, stream>>>(
            lw, (const float4*)part, b2, lpart, cN2 * 128 / 4, cN2 * 128, NBLK);
        k_linear_final<<<1, 640, 0, stream>>>(lpart, lb, outZ, NBLK);
    }
}

// Round 18
// 253.006 us; speedup vs baseline: 1.0052x; 1.0052x over previous
//
#include <hip/hip_runtime.h>

// ChebNet classifier: 3x ChebConv(K=6) + 2x sparse pool + linear head.
// R17 -> R18: ~30% of runtime is inter-dispatch bubbles (~3.5us x 23).
// Merged hop5+gemm5 for layers 1&2: block gathers its row-tile's tx5 into
// LDS (padded stride: no bank conflicts), __syncthreads, GEMMs from LDS ->
// part5. tx5 never hits global. Packs with gemm_4 blocks as before.
// Dispatches 24 -> 22, minus two tx5 round trips (~10MB).

#define TPB 256
#define NB   318      // buckets = ceil(162500/512)
#define BCAP 8192     // per-bucket capacity
#define EPB  4096     // edges per block, phase A
#define TXS  800000LL // floats per Tx slot

static inline int gs(long long n) { return (int)((n + TPB - 1) / TPB); }

struct Desc5 {
    const int* rows[5];
    const int* cols[5];
    const float* vals[5];
    int eoff[6];
    int doff[5];
};

// ---------- phase A: bin edges by bucket (+ packed pad4 blocks) ----------

__global__ void k_binA_pad(Desc5 d, int* __restrict__ gbcnt, int2* __restrict__ binrec,
                           int Etot, int binBlocks,
                           const float* __restrict__ pos, float4* __restrict__ pdst,
                           int npos) {
    __shared__ int2 srec[EPB];
    __shared__ unsigned short sbuck[EPB];
    __shared__ int scnt[NB], sbase[NB], slcur[NB];
    int tid = threadIdx.x;
    if ((int)blockIdx.x >= binBlocks) {
        int i = (blockIdx.x - binBlocks) * 256 + tid;
        if (i < npos)
            pdst[i] = make_float4(pos[3 * i], pos[3 * i + 1], pos[3 * i + 2], 0.f);
        return;
    }
    int e0 = blockIdx.x * EPB;
    int ne = min(EPB, Etot - e0);
    for (int b = tid; b < NB; b += 256) scnt[b] = 0;
    __syncthreads();
    for (int i = tid; i < ne; i += 256) {
        int e = e0 + i;
        int s = 0;
        while (e >= d.eoff[s + 1]) ++s;
        int le = e - d.eoff[s];
        int grow = d.doff[s] + d.rows[s][le];
        int col = d.cols[s][le];
        int vb = (s >= 3) ? __float_as_int(d.vals[s][le]) : 0;
        int b = grow >> 9;
        srec[i] = make_int2(((grow & 511) << 17) | col, vb);
        sbuck[i] = (unsigned short)b;
        atomicAdd(&scnt[b], 1);
    }
    __syncthreads();
    for (int b = tid; b < NB; b += 256) {
        sbase[b] = scnt[b] > 0 ? atomicAdd(&gbcnt[b], scnt[b]) : 0;
        slcur[b] = 0;
    }
    __syncthreads();
    for (int i = tid; i < ne; i += 256) {
        int b = sbuck[i];
        int off = atomicAdd(&slcur[b], 1);
        binrec[(long long)b * BCAP + sbase[b] + off] = srec[i];
    }
}

// B1: bucket-base scan + row count/scan -> rowptr + dinv
__global__ void k_B1(const int* __restrict__ gbcnt, const int2* __restrict__ binrec,
                     int* __restrict__ rowptr, float* __restrict__ dinv,
                     int ntot, int ndinv, int Etot) {
    __shared__ int cnt[512], lexcl[512], wsum[4];
    int bucket = blockIdx.x, tid = threadIdx.x;
    int lane = tid & 63, wid = tid >> 6;
    {
        int v0 = (2 * tid < NB) ? gbcnt[2 * tid] : 0;
        int v1 = (2 * tid + 1 < NB) ? gbcnt[2 * tid + 1] : 0;
        int p = v0 + v1;
        int s = p;
#pragma unroll
        for (int off = 1; off < 64; off <<= 1) {
            int t = __shfl_up(s, off, 64);
            if (lane >= off) s += t;
        }
        if (lane == 63) wsum[wid] = s;
        __syncthreads();
        int add = 0;
        for (int w = 0; w < wid; ++w) add += wsum[w];
        int ep = add + s - p;
        lexcl[2 * tid] = ep; lexcl[2 * tid + 1] = ep + v0;
        __syncthreads();
    }
    int base = lexcl[bucket];
    __syncthreads();
    int ne = gbcnt[bucket];
    const int2* br = binrec + (long long)bucket * BCAP;
    cnt[2 * tid] = 0; cnt[2 * tid + 1] = 0;
    __syncthreads();
    for (int i = tid; i < ne; i += 256)
        atomicAdd(&cnt[br[i].x >> 17], 1);
    __syncthreads();
    int c0 = cnt[2 * tid], c1 = cnt[2 * tid + 1], p = c0 + c1;
    int s = p;
#pragma unroll
    for (int off = 1; off < 64; off <<= 1) {
        int t = __shfl_up(s, off, 64);
        if (lane >= off) s += t;
    }
    if (lane == 63) wsum[wid] = s;
    __syncthreads();
    int add = 0;
    for (int w = 0; w < wid; ++w) add += wsum[w];
    int ep = add + s - p;
    lexcl[2 * tid] = ep; lexcl[2 * tid + 1] = ep + c0;
    __syncthreads();
    int row0 = bucket << 9;
    int nrows = min(512, ntot - row0);
    for (int lr = tid; lr < nrows; lr += 256) {
        int grow = row0 + lr;
        rowptr[grow] = base + lexcl[lr];
        if (grow < ndinv) {
            int c = cnt[lr];
            dinv[grow] = c > 0 ? 1.0f / sqrtf((float)c) : 0.f;
        }
    }
    if (bucket == 0 && tid == 0) rowptr[ntot] = Etot;
}

// B2: place edges using rowptr (LDS-staged)
__global__ void k_B2(const int* __restrict__ gbcnt, const int2* __restrict__ binrec,
                     const int* __restrict__ rowptr, const float* __restrict__ dinv,
                     int2* __restrict__ rec, int ntot) {
    __shared__ int lbase[512], lcur[512];
    int bucket = blockIdx.x, tid = threadIdx.x;
    int row0 = bucket << 9;
    for (int i = tid; i < 512; i += 256) {
        int grow = row0 + i;
        lbase[i] = (grow < ntot) ? rowptr[grow] : 0;
        lcur[i] = 0;
    }
    __syncthreads();
    int ne = gbcnt[bucket];
    const int2* br = binrec + (long long)bucket * BCAP;
    for (int i = tid; i < ne; i += 256) {
        int2 r = br[i];
        int lr = r.x >> 17, col = r.x & 0x1FFFF;
        int grow = row0 + lr;
        int pos = lbase[lr] + atomicAdd(&lcur[lr], 1);
        float wv;
        if (grow < 100000)      wv = dinv[col];
        else if (grow < 125000) wv = dinv[100000 + col];
        else if (grow < 131250) wv = dinv[125000 + col];
        else                    wv = __int_as_float(r.y);
        rec[pos] = make_int2(col, __float_as_int(wv));
    }
}

// ---------- pair-split sprop bodies ----------

// C == 4 (layer 0): pair-split, 2 chains per thread
__global__ void k_sprop_c4p(const int* __restrict__ rowptr, const int2* __restrict__ rec,
                            const float* __restrict__ dinv, const float* __restrict__ src,
                            const float* __restrict__ prev, float* __restrict__ dst,
                            int n, int mode) {
    int idx = blockIdx.x * blockDim.x + threadIdx.x;
    if (idx >= 2 * n) return;
    int r = idx >> 1, half = idx & 1;
    int s0 = rowptr[r], s1 = rowptr[r + 1];
    float4 a0 = make_float4(0.f, 0.f, 0.f, 0.f), a1 = a0;
    int j = s0 + half;
    for (; j + 2 < s1; j += 4) {
        int2 r0 = rec[j], r1 = rec[j + 2];
        float w0 = __int_as_float(r0.y), w1 = __int_as_float(r1.y);
        float4 s0v = *(const float4*)(src + (long long)r0.x * 4);
        float4 s1v = *(const float4*)(src + (long long)r1.x * 4);
        a0.x += w0 * s0v.x; a0.y += w0 * s0v.y; a0.z += w0 * s0v.z; a0.w += w0 * s0v.w;
        a1.x += w1 * s1v.x; a1.y += w1 * s1v.y; a1.z += w1 * s1v.z; a1.w += w1 * s1v.w;
    }
    if (j < s1) {
        int2 rr = rec[j];
        float w = __int_as_float(rr.y);
        float4 s = *(const float4*)(src + (long long)rr.x * 4);
        a0.x += w * s.x; a0.y += w * s.y; a0.z += w * s.z; a0.w += w * s.w;
    }
    a0.x += a1.x; a0.y += a1.y; a0.z += a1.z; a0.w += a1.w;
    a0.x += __shfl_xor(a0.x, 1, 64);
    a0.y += __shfl_xor(a0.y, 1, 64);
    a0.z += __shfl_xor(a0.z, 1, 64);
    a0.w += __shfl_xor(a0.w, 1, 64);
    if (half == 0) {
        float m = -dinv[r];
        long long o = (long long)r * 4;
        float4 out;
        if (mode) {
            float4 p = *(const float4*)(prev + o);
            out.x = 2.f * m * a0.x - p.x; out.y = 2.f * m * a0.y - p.y;
            out.z = 2.f * m * a0.z - p.z; out.w = 2.f * m * a0.w - p.w;
        } else {
            out.x = m * a0.x; out.y = m * a0.y; out.z = m * a0.z; out.w = m * a0.w;
        }
        *(float4*)(dst + o) = out;
    }
}

// pair-split 8-channel body (C=32): idx over n*4*2
__device__ __forceinline__
void sprop32p_body(const int* __restrict__ rowptr, const int2* __restrict__ rec,
                   const float* __restrict__ dinv, const float* __restrict__ src,
                   const float* __restrict__ prev, float* __restrict__ dst,
                   int n, int mode, int idx) {
    constexpr int C = 32;
    if (idx >= n * 8) return;
    int cid = idx >> 1, half = idx & 1;
    int r = cid >> 2, c4 = (cid & 3) * 8;
    int s0 = rowptr[r], s1 = rowptr[r + 1];
    float4 a0 = make_float4(0.f, 0.f, 0.f, 0.f), a1 = a0;
    for (int j = s0 + half; j < s1; j += 2) {
        int2 rr = rec[j];
        float w = __int_as_float(rr.y);
        const float* sp = src + (long long)rr.x * C + c4;
        float4 s0v = *(const float4*)(sp);
        float4 s1v = *(const float4*)(sp + 4);
        a0.x += w * s0v.x; a0.y += w * s0v.y; a0.z += w * s0v.z; a0.w += w * s0v.w;
        a1.x += w * s1v.x; a1.y += w * s1v.y; a1.z += w * s1v.z; a1.w += w * s1v.w;
    }
    a0.x += __shfl_xor(a0.x, 1, 64); a0.y += __shfl_xor(a0.y, 1, 64);
    a0.z += __shfl_xor(a0.z, 1, 64); a0.w += __shfl_xor(a0.w, 1, 64);
    a1.x += __shfl_xor(a1.x, 1, 64); a1.y += __shfl_xor(a1.y, 1, 64);
    a1.z += __shfl_xor(a1.z, 1, 64); a1.w += __shfl_xor(a1.w, 1, 64);
    if (half == 0) {
        float m = -dinv[r];
        long long o = (long long)r * C + c4;
        float4 o0, o1;
        if (mode) {
            float4 p0 = *(const float4*)(prev + o);
            float4 p1 = *(const float4*)(prev + o + 4);
            o0.x = 2.f * m * a0.x - p0.x; o0.y = 2.f * m * a0.y - p0.y;
            o0.z = 2.f * m * a0.z - p0.z; o0.w = 2.f * m * a0.w - p0.w;
            o1.x = 2.f * m * a1.x - p1.x; o1.y = 2.f * m * a1.y - p1.y;
            o1.z = 2.f * m * a1.z - p1.z; o1.w = 2.f * m * a1.w - p1.w;
        } else {
            o0.x = m * a0.x; o0.y = m * a0.y; o0.z = m * a0.z; o0.w = m * a0.w;
            o1.x = m * a1.x; o1.y = m * a1.y; o1.z = m * a1.z; o1.w = m * a1.w;
        }
        *(float4*)(dst + o) = o0;
        *(float4*)(dst + o + 4) = o1;
    }
}

// pair-split 4-channel body (C=64): idx over n*16*2
__device__ __forceinline__
void sprop64p_body(const int* __restrict__ rowptr, const int2* __restrict__ rec,
                   const float* __restrict__ dinv, const float* __restrict__ src,
                   const float* __restrict__ prev, float* __restrict__ dst,
                   int n, int mode, int idx) {
    constexpr int C = 64, C4 = 16;
    if (idx >= n * C4 * 2) return;
    int cid = idx >> 1, half = idx & 1;
    int r = cid / C4, c4 = (cid - r * C4) * 4;
    int s0 = rowptr[r], s1 = rowptr[r + 1];
    float4 a0 = make_float4(0.f, 0.f, 0.f, 0.f), a1 = a0;
    int j = s0 + half;
    for (; j + 2 < s1; j += 4) {
        int2 r0 = rec[j], r1 = rec[j + 2];
        float w0 = __int_as_float(r0.y), w1 = __int_as_float(r1.y);
        float4 s0v = *(const float4*)(src + (long long)r0.x * C + c4);
        float4 s1v = *(const float4*)(src + (long long)r1.x * C + c4);
        a0.x += w0 * s0v.x; a0.y += w0 * s0v.y; a0.z += w0 * s0v.z; a0.w += w0 * s0v.w;
        a1.x += w1 * s1v.x; a1.y += w1 * s1v.y; a1.z += w1 * s1v.z; a1.w += w1 * s1v.w;
    }
    if (j < s1) {
        int2 rr = rec[j];
        float w = __int_as_float(rr.y);
        float4 s = *(const float4*)(src + (long long)rr.x * C + c4);
        a0.x += w * s.x; a0.y += w * s.y; a0.z += w * s.z; a0.w += w * s.w;
    }
    a0.x += a1.x; a0.y += a1.y; a0.z += a1.z; a0.w += a1.w;
    a0.x += __shfl_xor(a0.x, 1, 64); a0.y += __shfl_xor(a0.y, 1, 64);
    a0.z += __shfl_xor(a0.z, 1, 64); a0.w += __shfl_xor(a0.w, 1, 64);
    if (half == 0) {
        float m = -dinv[r];
        long long o = (long long)r * C + c4;
        float4 out;
        if (mode) {
            float4 p = *(const float4*)(prev + o);
            out.x = 2.f * m * a0.x - p.x; out.y = 2.f * m * a0.y - p.y;
            out.z = 2.f * m * a0.z - p.z; out.w = 2.f * m * a0.w - p.w;
        } else {
            out.x = m * a0.x; out.y = m * a0.y; out.z = m * a0.z; out.w = m * a0.w;
        }
        *(float4*)(dst + o) = out;
    }
}

// ---------- per-k gemm body: part_k = tx_k @ W[k] (forced-loop, no spill) ----------

template <int CIN, int COUT, int NT>
__device__ __forceinline__
void gemm1k_body(float* __restrict__ part, const float* __restrict__ txbase,
                 const float* __restrict__ W, int n, int pstride, int kg, int idx) {
    constexpr int CO4 = COUT / 4;
    int per = (n / NT) * CO4;
    if (idx >= per) return;
    int tile = idx / CO4, co = (idx - tile * CO4) * 4;
    int node0 = tile * NT;
    float4 acc[NT];
#pragma unroll
    for (int i = 0; i < NT; ++i) acc[i] = make_float4(0.f, 0.f, 0.f, 0.f);
    const float* xb = txbase + (long long)kg * TXS + (long long)node0 * CIN;
    const float* Wk = W + (long long)kg * CIN * COUT + co;
#pragma unroll 1
    for (int c4 = 0; c4 < CIN / 4; ++c4) {
        const float* Wr = Wk + c4 * 4 * COUT;
        float4 w0 = *(const float4*)(Wr);
        float4 w1 = *(const float4*)(Wr + COUT);
        float4 w2 = *(const float4*)(Wr + 2 * COUT);
        float4 w3 = *(const float4*)(Wr + 3 * COUT);
#pragma unroll
        for (int i = 0; i < NT; ++i) {
            float4 xv = *(const float4*)(xb + i * CIN + c4 * 4);
            acc[i].x += xv.x * w0.x + xv.y * w1.x + xv.z * w2.x + xv.w * w3.x;
            acc[i].y += xv.x * w0.y + xv.y * w1.y + xv.z * w2.y + xv.w * w3.y;
            acc[i].z += xv.x * w0.z + xv.y * w1.z + xv.z * w2.z + xv.w * w3.z;
            acc[i].w += xv.x * w0.w + xv.y * w1.w + xv.z * w2.w + xv.w * w3.w;
        }
    }
    float* op = part + (long long)kg * pstride + (long long)node0 * COUT + co;
#pragma unroll
    for (int i = 0; i < NT; ++i)
        *(float4*)(op + (long long)i * COUT) = acc[i];
}

// ---------- packed launches: sprop hop (blocks [0,SB)) + gemm_k (rest) ----------

__global__ __launch_bounds__(256, 4)
void k_pack1(const int* __restrict__ rowptr, const int2* __restrict__ rec,
             const float* __restrict__ dinv, const float* __restrict__ src,
             const float* __restrict__ prev, float* __restrict__ dst,
             int n, int mode, float* __restrict__ part,
             const float* __restrict__ txbase, const float* __restrict__ W,
             int pstride, int kg, int spropBlocks) {
    int bid = blockIdx.x;
    if (bid < spropBlocks)
        sprop32p_body(rowptr, rec, dinv, src, prev, dst, n, mode,
                      bid * 256 + threadIdx.x);
    else
        gemm1k_body<32, 64, 4>(part, txbase, W, n, pstride, kg,
                               (bid - spropBlocks) * 256 + threadIdx.x);
}

__global__ __launch_bounds__(256, 4)
void k_pack2(const int* __restrict__ rowptr, const int2* __restrict__ rec,
             const float* __restrict__ dinv, const float* __restrict__ src,
             const float* __restrict__ prev, float* __restrict__ dst,
             int n, int mode, float* __restrict__ part,
             const float* __restrict__ txbase, const float* __restrict__ W,
             int pstride, int kg, int spropBlocks) {
    int bid = blockIdx.x;
    if (bid < spropBlocks)
        sprop64p_body(rowptr, rec, dinv, src, prev, dst, n, mode,
                      bid * 256 + threadIdx.x);
    else
        gemm1k_body<64, 128, 2>(part, txbase, W, n, pstride, kg,
                                (bid - spropBlocks) * 256 + threadIdx.x);
}

// ---------- merged hop5+gemm5 (layer 1): tx5 tile in LDS, GEMM from LDS ----------
// R=32 rows/block; gather item = (row_local, c4 of 8); gemm out = row x 16 co4.

__device__ __forceinline__
void convf1_body(const int* __restrict__ rowptr, const int2* __restrict__ rec,
                 const float* __restrict__ dinv, const float* __restrict__ txbase,
                 const float* __restrict__ W, float* __restrict__ part,
                 int n, int pstride, int bid, float (*ltx)[36]) {
    constexpr int C = 32;
    int tid = threadIdx.x;
    int row0 = bid * 32;
    const float* src = txbase + 4 * TXS;   // tx4
    const float* prv = txbase + 3 * TXS;   // tx3
    {
        int rl = tid >> 3, c4 = (tid & 7) * 4;
        int r = row0 + rl;
        if (r < n) {
            int s0 = rowptr[r], s1 = rowptr[r + 1];
            float4 a0 = make_float4(0.f, 0.f, 0.f, 0.f), a1 = a0;
            int j = s0;
            for (; j + 2 <= s1; j += 2) {
                int2 q0 = rec[j], q1 = rec[j + 1];
                float w0 = __int_as_float(q0.y), w1 = __int_as_float(q1.y);
                float4 s0v = *(const float4*)(src + (long long)q0.x * C + c4);
                float4 s1v = *(const float4*)(src + (long long)q1.x * C + c4);
                a0.x += w0 * s0v.x; a0.y += w0 * s0v.y; a0.z += w0 * s0v.z; a0.w += w0 * s0v.w;
                a1.x += w1 * s1v.x; a1.y += w1 * s1v.y; a1.z += w1 * s1v.z; a1.w += w1 * s1v.w;
            }
            if (j < s1) {
                int2 q = rec[j];
                float w = __int_as_float(q.y);
                float4 s = *(const float4*)(src + (long long)q.x * C + c4);
                a0.x += w * s.x; a0.y += w * s.y; a0.z += w * s.z; a0.w += w * s.w;
            }
            a0.x += a1.x; a0.y += a1.y; a0.z += a1.z; a0.w += a1.w;
            float m = -dinv[r];
            float4 p = *(const float4*)(prv + (long long)r * C + c4);
            ltx[rl][c4]     = 2.f * m * a0.x - p.x;
            ltx[rl][c4 + 1] = 2.f * m * a0.y - p.y;
            ltx[rl][c4 + 2] = 2.f * m * a0.z - p.z;
            ltx[rl][c4 + 3] = 2.f * m * a0.w - p.w;
        }
    }
    __syncthreads();
    const float* Wk = W + 5 * 32 * 64;
#pragma unroll
    for (int half = 0; half < 2; ++half) {
        int out_id = half * 256 + tid;       // 512 outputs: 32 rows x 16 co4
        int rl = out_id >> 4, co = (out_id & 15) * 4;
        int r = row0 + rl;
        if (r >= n) continue;
        float4 acc = make_float4(0.f, 0.f, 0.f, 0.f);
#pragma unroll 1
        for (int c4 = 0; c4 < 8; ++c4) {
            const float* Wr = Wk + c4 * 4 * 64 + co;
            float4 w0 = *(const float4*)(Wr);
            float4 w1 = *(const float4*)(Wr + 64);
            float4 w2 = *(const float4*)(Wr + 128);
            float4 w3 = *(const float4*)(Wr + 192);
            float4 xv = *(const float4*)(&ltx[rl][c4 * 4]);
            acc.x += xv.x * w0.x + xv.y * w1.x + xv.z * w2.x + xv.w * w3.x;
            acc.y += xv.x * w0.y + xv.y * w1.y + xv.z * w2.y + xv.w * w3.y;
            acc.z += xv.x * w0.z + xv.y * w1.z + xv.z * w2.z + xv.w * w3.z;
            acc.w += xv.x * w0.w + xv.y * w1.w + xv.z * w2.w + xv.w * w3.w;
        }
        *(float4*)(part + 5LL * pstride + (long long)r * 64 + co) = acc;
    }
}

// merged hop5+gemm5 (layer 2): R=16 rows/block, C=64, COUT=128
__device__ __forceinline__
void convf2_body(const int* __restrict__ rowptr, const int2* __restrict__ rec,
                 const float* __restrict__ dinv, const float* __restrict__ txbase,
                 const float* __restrict__ W, float* __restrict__ part,
                 int n, int pstride, int bid, float (*ltx)[68]) {
    constexpr int C = 64;
    int tid = threadIdx.x;
    int row0 = bid * 16;
    const float* src = txbase + 4 * TXS;   // tx4
    const float* prv = txbase + 3 * TXS;   // tx3
    {
        int rl = tid >> 4, c4 = (tid & 15) * 4;
        int r = row0 + rl;
        if (r < n) {
            int s0 = rowptr[r], s1 = rowptr[r + 1];
            float4 a0 = make_float4(0.f, 0.f, 0.f, 0.f), a1 = a0;
            int j = s0;
            for (; j + 2 <= s1; j += 2) {
                int2 q0 = rec[j], q1 = rec[j + 1];
                float w0 = __int_as_float(q0.y), w1 = __int_as_float(q1.y);
                float4 s0v = *(const float4*)(src + (long long)q0.x * C + c4);
                float4 s1v = *(const float4*)(src + (long long)q1.x * C + c4);
                a0.x += w0 * s0v.x; a0.y += w0 * s0v.y; a0.z += w0 * s0v.z; a0.w += w0 * s0v.w;
                a1.x += w1 * s1v.x; a1.y += w1 * s1v.y; a1.z += w1 * s1v.z; a1.w += w1 * s1v.w;
            }
            if (j < s1) {
                int2 q = rec[j];
                float w = __int_as_float(q.y);
                float4 s = *(const float4*)(src + (long long)q.x * C + c4);
                a0.x += w * s.x; a0.y += w * s.y; a0.z += w * s.z; a0.w += w * s.w;
            }
            a0.x += a1.x; a0.y += a1.y; a0.z += a1.z; a0.w += a1.w;
            float m = -dinv[r];
            float4 p = *(const float4*)(prv + (long long)r * C + c4);
            ltx[rl][c4]     = 2.f * m * a0.x - p.x;
            ltx[rl][c4 + 1] = 2.f * m * a0.y - p.y;
            ltx[rl][c4 + 2] = 2.f * m * a0.z - p.z;
            ltx[rl][c4 + 3] = 2.f * m * a0.w - p.w;
        }
    }
    __syncthreads();
    const float* Wk = W + 5 * 64 * 128;
#pragma unroll
    for (int half = 0; half < 2; ++half) {
        int out_id = half * 256 + tid;       // 512 outputs: 16 rows x 32 co4
        int rl = out_id >> 5, co = (out_id & 31) * 4;
        int r = row0 + rl;
        if (r >= n) continue;
        float4 acc = make_float4(0.f, 0.f, 0.f, 0.f);
#pragma unroll 1
        for (int c4 = 0; c4 < 16; ++c4) {
            const float* Wr = Wk + c4 * 4 * 128 + co;
            float4 w0 = *(const float4*)(Wr);
            float4 w1 = *(const float4*)(Wr + 128);
            float4 w2 = *(const float4*)(Wr + 256);
            float4 w3 = *(const float4*)(Wr + 384);
            float4 xv = *(const float4*)(&ltx[rl][c4 * 4]);
            acc.x += xv.x * w0.x + xv.y * w1.x + xv.z * w2.x + xv.w * w3.x;
            acc.y += xv.x * w0.y + xv.y * w1.y + xv.z * w2.y + xv.w * w3.y;
            acc.z += xv.x * w0.z + xv.y * w1.z + xv.z * w2.z + xv.w * w3.z;
            acc.w += xv.x * w0.w + xv.y * w1.w + xv.z * w2.w + xv.w * w3.w;
        }
        *(float4*)(part + 5LL * pstride + (long long)r * 128 + co) = acc;
    }
}

// final packed launches: merged hop5+gemm5 blocks [0,fB) + gemm_4 blocks [fB,..)
__global__ __launch_bounds__(256, 4)
void k_packf1(const int* __restrict__ rowptr, const int2* __restrict__ rec,
              const float* __restrict__ dinv, const float* __restrict__ txbase,
              const float* __restrict__ W, float* __restrict__ part,
              int n, int pstride, int fB) {
    __shared__ float ltx[32][36];
    int bid = blockIdx.x;
    if (bid < fB)
        convf1_body(rowptr, rec, dinv, txbase, W, part, n, pstride, bid, ltx);
    else
        gemm1k_body<32, 64, 4>(part, txbase, W, n, pstride, 4,
                               (bid - fB) * 256 + threadIdx.x);
}

__global__ __launch_bounds__(256, 4)
void k_packf2(const int* __restrict__ rowptr, const int2* __restrict__ rec,
              const float* __restrict__ dinv, const float* __restrict__ txbase,
              const float* __restrict__ W, float* __restrict__ part,
              int n, int pstride, int fB) {
    __shared__ float ltx[16][68];
    int bid = blockIdx.x;
    if (bid < fB)
        convf2_body(rowptr, rec, dinv, txbase, W, part, n, pstride, bid, ltx);
    else
        gemm1k_body<64, 128, 2>(part, txbase, W, n, pstride, 4,
                                (bid - fB) * 256 + threadIdx.x);
}

// layer-0 FINAL hop fused with the out-GEMM (node-local)
__global__ __launch_bounds__(256, 4)
void k_conv0_final(const int* __restrict__ rowptr, const int2* __restrict__ rec,
                   const float* __restrict__ dinv, const float* __restrict__ txbase,
                   const float* __restrict__ W, const float* __restrict__ b,
                   float* __restrict__ out, int n) {
    int r = blockIdx.x * blockDim.x + threadIdx.x;
    if (r >= n) return;
    const float* src = txbase + 4 * TXS;   // tx4
    int s0 = rowptr[r], s1 = rowptr[r + 1];
    float4 a0 = make_float4(0.f, 0.f, 0.f, 0.f);
    float4 a1 = a0;
    int j = s0;
    if ((j & 1) && j < s1) {
        int2 rr = rec[j];
        float w = __int_as_float(rr.y);
        float4 s = *(const float4*)(src + (long long)rr.x * 4);
        a0.x += w * s.x; a0.y += w * s.y; a0.z += w * s.z;
        ++j;
    }
    for (; j + 2 <= s1; j += 2) {
        int4 q = *(const int4*)(rec + j);
        float wa = __int_as_float(q.y), wb = __int_as_float(q.w);
        float4 sa = *(const float4*)(src + (long long)q.x * 4);
        float4 sb = *(const float4*)(src + (long long)q.z * 4);
        a0.x += wa * sa.x; a0.y += wa * sa.y; a0.z += wa * sa.z;
        a1.x += wb * sb.x; a1.y += wb * sb.y; a1.z += wb * sb.z;
    }
    if (j < s1) {
        int2 rr = rec[j];
        float w = __int_as_float(rr.y);
        float4 s = *(const float4*)(src + (long long)rr.x * 4);
        a0.x += w * s.x; a0.y += w * s.y; a0.z += w * s.z;
    }
    a0.x += a1.x; a0.y += a1.y; a0.z += a1.z;
    float m = -dinv[r];
    float4 xv[6];
#pragma unroll
    for (int k = 0; k < 5; ++k)
        xv[k] = *(const float4*)(txbase + (long long)k * TXS + (long long)r * 4);
    xv[5].x = 2.f * m * a0.x - xv[3].x;
    xv[5].y = 2.f * m * a0.y - xv[3].y;
    xv[5].z = 2.f * m * a0.z - xv[3].z;
    float* op = out + (long long)r * 32;
#pragma unroll 1
    for (int co4 = 0; co4 < 8; ++co4) {
        float4 acc = *(const float4*)(b + co4 * 4);
#pragma unroll
        for (int k = 0; k < 6; ++k) {
            const float* Wk = W + k * 96 + co4 * 4;
            float4 w0 = *(const float4*)(Wk);
            float4 w1 = *(const float4*)(Wk + 32);
            float4 w2 = *(const float4*)(Wk + 64);
            acc.x += xv[k].x * w0.x + xv[k].y * w1.x + xv[k].z * w2.x;
            acc.y += xv[k].x * w0.y + xv[k].y * w1.y + xv[k].z * w2.y;
            acc.z += xv[k].x * w0.z + xv[k].y * w1.z + xv[k].z * w2.z;
            acc.w += xv[k].x * w0.w + xv[k].y * w1.w + xv[k].z * w2.w;
        }
        *(float4*)(op + co4 * 4) = acc;
    }
}

// ---------- pool0: out[r] = sum_j val_j * relu(x[col_j]) ----------

template <int C>
__global__ void k_spool4_t(const int* __restrict__ rowptr, const int2* __restrict__ rec,
                           const float* __restrict__ x, float* __restrict__ out, int n) {
    constexpr int C4 = C / 4;
    int idx = blockIdx.x * blockDim.x + threadIdx.x;
    if (idx >= n * C4) return;
    int r = idx / C4, c4 = (idx - r * C4) * 4;
    int s0 = rowptr[r], s1 = rowptr[r + 1];
    float4 acca = make_float4(0.f, 0.f, 0.f, 0.f);
    float4 accb = make_float4(0.f, 0.f, 0.f, 0.f);
    int j = s0;
    if ((j & 1) && j < s1) {
        int2 rr = rec[j];
        float v = __int_as_float(rr.y);
        float4 s = *(const float4*)(x + (long long)rr.x * C + c4);
        acca.x += v * fmaxf(s.x, 0.f); acca.y += v * fmaxf(s.y, 0.f);
        acca.z += v * fmaxf(s.z, 0.f); acca.w += v * fmaxf(s.w, 0.f);
        ++j;
    }
    for (; j + 2 <= s1; j += 2) {
        int4 q = *(const int4*)(rec + j);
        float va = __int_as_float(q.y), vb = __int_as_float(q.w);
        float4 sa = *(const float4*)(x + (long long)q.x * C + c4);
        float4 sb = *(const float4*)(x + (long long)q.z * C + c4);
        acca.x += va * fmaxf(sa.x, 0.f); acca.y += va * fmaxf(sa.y, 0.f);
        acca.z += va * fmaxf(sa.z, 0.f); acca.w += va * fmaxf(sa.w, 0.f);
        accb.x += vb * fmaxf(sb.x, 0.f); accb.y += vb * fmaxf(sb.y, 0.f);
        accb.z += vb * fmaxf(sb.z, 0.f); accb.w += vb * fmaxf(sb.w, 0.f);
    }
    if (j < s1) {
        int2 rr = rec[j];
        float v = __int_as_float(rr.y);
        float4 s = *(const float4*)(x + (long long)rr.x * C + c4);
        acca.x += v * fmaxf(s.x, 0.f); acca.y += v * fmaxf(s.y, 0.f);
        acca.z += v * fmaxf(s.z, 0.f); acca.w += v * fmaxf(s.w, 0.f);
    }
    acca.x += accb.x; acca.y += accb.y; acca.z += accb.z; acca.w += accb.w;
    *(float4*)(out + (long long)r * C + c4) = acca;
}

// ---------- pool1 fused with layer-1 partial reduce + bias + relu ----------

template <int C, int KSPLIT>
__global__ void k_pool_f(const int* __restrict__ rowptr, const int2* __restrict__ rec,
                         const float* __restrict__ part, const float* __restrict__ bias,
                         float* __restrict__ out, int n, int partStride) {
    constexpr int C4 = C / 4;
    int idx = blockIdx.x * blockDim.x + threadIdx.x;
    if (idx >= n * C4) return;
    int r = idx / C4, c4 = (idx - r * C4) * 4;
    int s0 = rowptr[r], s1 = rowptr[r + 1];
    float4 bb = *(const float4*)(bias + c4);
    float4 acc = make_float4(0.f, 0.f, 0.f, 0.f);
    for (int j = s0; j < s1; ++j) {
        int2 rr = rec[j];
        float v = __int_as_float(rr.y);
        float4 x = bb;
#pragma unroll
        for (int s = 0; s < KSPLIT; ++s) {
            float4 p = *(const float4*)(part + (long long)s * partStride + (long long)rr.x * C + c4);
            x.x += p.x; x.y += p.y; x.z += p.z; x.w += p.w;
        }
        acc.x += v * fmaxf(x.x, 0.f); acc.y += v * fmaxf(x.y, 0.f);
        acc.z += v * fmaxf(x.z, 0.f); acc.w += v * fmaxf(x.w, 0.f);
    }
    *(float4*)(out + (long long)r * C + c4) = acc;
}

// ---------- linear head, fused with layer-2 partial reduce + bias ----------

__global__ void k_linear_partial_f(const float* __restrict__ lw,
                                   const float4* __restrict__ part,
                                   const float* __restrict__ b2,
                                   float* __restrict__ partials,
                                   int len4, int len, int nblk) {
    float acc[10];
#pragma unroll
    for (int j = 0; j < 10; ++j) acc[j] = 0.f;
    const float4* b2v = (const float4*)b2;
    for (int i = blockIdx.x * blockDim.x + threadIdx.x; i < len4;
         i += gridDim.x * blockDim.x) {
        float4 xv = b2v[i & 31];
#pragma unroll
        for (int s = 0; s < 6; ++s) {
            float4 p = part[s * 200000 + i];
            xv.x += p.x; xv.y += p.y; xv.z += p.z; xv.w += p.w;
        }
#pragma unroll
        for (int j = 0; j < 10; ++j) {
            float4 wv = *(const float4*)(lw + (long long)j * len + i * 4);
            acc[j] += xv.x * wv.x + xv.y * wv.y + xv.z * wv.z + xv.w * wv.w;
        }
    }
    __shared__ float lds[4][10];
    int wid = threadIdx.x >> 6, lane = threadIdx.x & 63;
#pragma unroll
    for (int j = 0; j < 10; ++j) {
        float v = acc[j];
        for (int off = 32; off > 0; off >>= 1) v += __shfl_down(v, off, 64);
        if (lane == 0) lds[wid][j] = v;
    }
    __syncthreads();
    if (threadIdx.x < 10) {
        float s = lds[0][threadIdx.x] + lds[1][threadIdx.x] +
                  lds[2][threadIdx.x] + lds[3][threadIdx.x];
        partials[threadIdx.x * nblk + blockIdx.x] = s;
    }
}

__global__ void k_linear_final(const float* __restrict__ partials,
                               const float* __restrict__ lb,
                               float* __restrict__ out, int nblk) {
    int j = threadIdx.x >> 6, lane = threadIdx.x & 63;
    float v = 0.f;
    for (int b = lane; b < nblk; b += 64) v += partials[j * nblk + b];
    for (int off = 32; off > 0; off >>= 1) v += __shfl_down(v, off, 64);
    if (lane == 0) out[j] = lb[j] + v;
}

extern "C" void kernel_launch(void* const* d_in, const int* in_sizes, int n_in,
                              void* d_out, int out_size, void* d_ws, size_t ws_size,
                              hipStream_t stream) {
    const int cN0 = 100000, cN1 = 25000, cN2 = 6250;
    const int cE0 = 600000, cE1 = 150000, cE2 = 40000;
    const int NBLK = 512;

    const float* pos = (const float*)d_in[0];
    const int*   ei0 = (const int*)d_in[1];
    const int*   ei1 = (const int*)d_in[2];
    const int*   ei2 = (const int*)d_in[3];
    const int*   d0r = (const int*)d_in[4];
    const int*   d0c = (const int*)d_in[5];
    const float* d0v = (const float*)d_in[6];
    const int*   d1r = (const int*)d_in[7];
    const int*   d1c = (const int*)d_in[8];
    const float* d1v = (const float*)d_in[9];
    const float* W0  = (const float*)d_in[10];
    const float* b0  = (const float*)d_in[11];
    const float* W1  = (const float*)d_in[12];
    const float* b1  = (const float*)d_in[13];
    const float* W2  = (const float*)d_in[14];
    const float* b2  = (const float*)d_in[15];
    const float* lw  = (const float*)d_in[16];
    const float* lb  = (const float*)d_in[17];
    float* outZ = (float*)d_out;

    // concatenated row space: g0 g1 g2 p0 p1
    const int ntot = cN0 + cN1 + cN2 + cN1 + cN2;          // 162500
    const int Etot = cE0 + cE1 + cE2 + cN0 + cN1;          // 915000
    const int Eg   = cE0 + cE1 + cE2;                      // 790000
    const int ndinv = cN0 + cN1 + cN2;                     // 131250
    const int doff0 = 0, doff1 = cN0, doff2 = cN0 + cN1,
              doffp0 = doff2 + cN2, doffp1 = doffp0 + cN1;

    // workspace layout (4B units); int2/float4 bases 16B-aligned
    int*   iws    = (int*)d_ws;
    int*   gbcnt  = iws;                          // 320
    int*   rowptr = gbcnt + 320;                  // 162504
    float* dinv   = (float*)(rowptr + 162504);    // 131256
    int2*  binrec = (int2*)(dinv + 131256);       // NB*BCAP int2
    int2*  rec    = binrec + (long long)NB * BCAP;// 915000 int2
    float* txbuf  = (float*)(rec + 915000);       // 6 x TXS (slot 0 = x)
    float* part   = txbuf + 6 * TXS;              // 6 x 1600000 (layer-1 max)
    float* bufOut = part + 9600000;               // 3200000
    float* lpart  = bufOut + 3200000;             // 5120

    Desc5 d;
    d.rows[0] = ei0;        d.cols[0] = ei0 + cE0; d.vals[0] = nullptr;
    d.rows[1] = ei1;        d.cols[1] = ei1 + cE1; d.vals[1] = nullptr;
    d.rows[2] = ei2;        d.cols[2] = ei2 + cE2; d.vals[2] = nullptr;
    d.rows[3] = d0r;        d.cols[3] = d0c;       d.vals[3] = d0v;
    d.rows[4] = d1r;        d.cols[4] = d1c;       d.vals[4] = d1v;
    d.eoff[0] = 0;
    d.eoff[1] = cE0;
    d.eoff[2] = cE0 + cE1;
    d.eoff[3] = Eg;
    d.eoff[4] = Eg + cN0;
    d.eoff[5] = Etot;
    d.doff[0] = doff0; d.doff[1] = doff1; d.doff[2] = doff2;
    d.doff[3] = doffp0; d.doff[4] = doffp1;

    // ---- binned CSR build + packed pad4 ----
    hipMemsetAsync(gbcnt, 0, (size_t)NB * 4, stream);
    int binBlocks = (Etot + EPB - 1) / EPB;               // 224
    int padBlocks = gs(cN0);                              // 391
    k_binA_pad<<<binBlocks + padBlocks, TPB, 0, stream>>>(
        d, gbcnt, binrec, Etot, binBlocks, pos, (float4*)txbuf, cN0);
    k_B1<<<NB, TPB, 0, stream>>>(gbcnt, binrec, rowptr, dinv, ntot, ndinv, Etot);
    k_B2<<<NB, TPB, 0, stream>>>(gbcnt, binrec, rowptr, dinv, rec, ntot);

    // ---- layer 0: pair-split hops 1..4, fused hop-5 + out-GEMM; pool0 ----
    for (int k = 1; k <= 4; ++k) {
        const float* src = txbuf + (long long)(k - 1) * TXS;
        const float* prev = (k >= 2) ? txbuf + (long long)(k - 2) * TXS : nullptr;
        float* dst = txbuf + (long long)k * TXS;
        k_sprop_c4p<<<gs((long long)cN0 * 2), TPB, 0, stream>>>(
            rowptr + doff0, rec, dinv + doff0, src, prev, dst, cN0, k >= 2 ? 1 : 0);
    }
    k_conv0_final<<<gs(cN0), TPB, 0, stream>>>(
        rowptr + doff0, rec, dinv + doff0, txbuf, W0, b0, bufOut, cN0);
    k_spool4_t<32><<<gs((long long)cN1 * 8), TPB, 0, stream>>>(
        rowptr + doffp0, rec, bufOut, txbuf, cN1);

    // ---- layer 1: packed hops 1..4 (+gemm_0..3); merged hop5+gemm5 (+gemm_4);
    //      pool (sums parts 0..5) ----
    {
        const int pstride = cN1 * 64;                      // 1600000
        int sB = gs((long long)cN1 * 8);                   // 782 (pair-split)
        int gB = gs((long long)(cN1 / 4) * 16);            // 391
        for (int k = 1; k <= 4; ++k) {
            const float* src = txbuf + (long long)(k - 1) * TXS;
            const float* prev = (k >= 2) ? txbuf + (long long)(k - 2) * TXS : nullptr;
            float* dst = txbuf + (long long)k * TXS;
            k_pack1<<<sB + gB, TPB, 0, stream>>>(
                rowptr + doff1, rec, dinv + doff1, src, prev, dst, cN1,
                k >= 2 ? 1 : 0, part, txbuf, W1, pstride, k - 1, sB);
        }
        int fB = (cN1 + 31) / 32;                          // 782
        k_packf1<<<fB + gB, TPB, 0, stream>>>(
            rowptr + doff1, rec, dinv + doff1, txbuf, W1, part, cN1, pstride, fB);
        k_pool_f<64, 6><<<gs((long long)cN2 * 16), TPB, 0, stream>>>(
            rowptr + doffp1, rec, part, b1, txbuf, cN2, pstride);
    }

    // ---- layer 2: packed hops 1..4; merged hop5+gemm5 (+gemm_4); head ----
    {
        const int pstride = cN2 * 128;                     // 800000
        int sB = gs((long long)cN2 * 32);                  // 782 (pair-split)
        int gB = gs((long long)(cN2 / 2) * 32);            // 391
        for (int k = 1; k <= 4; ++k) {
            const float* src = txbuf + (long long)(k - 1) * TXS;
            const float* prev = (k >= 2) ? txbuf + (long long)(k - 2) * TXS : nullptr;
            float* dst = txbuf + (long long)k * TXS;
            k_pack2<<<sB + gB, TPB, 0, stream>>>(
                rowptr + doff2, rec, dinv + doff2, src, prev, dst, cN2,
                k >= 2 ? 1 : 0, part, txbuf, W2, pstride, k - 1, sB);
        }
        int fB = (cN2 + 15) / 16;                          // 391
        k_packf2<<<fB + gB, TPB, 0, stream>>>(
            rowptr + doff2, rec, dinv + doff2, txbuf, W2, part, cN2, pstride, fB);
        k_linear_partial_f<<<NBLK, TPB, 0, stream>>>(
            lw, (const float4*)part, b2, lpart, cN2 * 128 / 4, cN2 * 128, NBLK);
        k_linear_final<<<1, 640, 0, stream>>>(lpart, lb, outZ, NBLK);
    }
}